// Round 11
// baseline (572.885 us; speedup 1.0000x reference)
//
#include <hip/hip_runtime.h>

#define NN 2048
#define NE 32768
#define DF 2048
#define TOPK 20
#define RMAXF 1e-5f
#define MAXD 48           // supported max in-degree (Poisson(16); verified by passing rounds)
#define MAXDQ (MAXD / 4)  // 12 quad-levels of 4 packed edges
#define SENTW 0x08000800u // two packed sentinel slot-ids (2048 -> PV[2048] == 0)
#define NSRC 4            // sources per block (float4-packed PV)
#define MAXROUNDS 64      // safety cap; provably unreachable (mass halves/round)
#define NL 4              // owned slots per thread (512 threads)

typedef __attribute__((ext_vector_type(4))) float f32x4;
typedef unsigned long long u64;

// ---------------- init: sentinel-fill transposed in-edge table ----------------
__global__ __launch_bounds__(256) void init_kernel(unsigned* __restrict__ T) {
    int i = blockIdx.x * 256 + threadIdx.x;
    if (i < MAXDQ * NN * 2) T[i] = SENTW;
}

// ---------------- meta: degree count (fused) + degree-sorted SNAKE slot permutation ----------------
// Degrees via LDS histogram (one coalesced edge pass; replaces the count_kernel launch +
// its global-atomic pass). Counting sort by in-degree (round-7 win: wave-uniform gather
// bound ~= local mean). Snake placement (round-10): sorted rank t -> stratum q = t>>9,
// within-stratum group s = (t>>6)&7, physical group q*8 + (q odd ? 7-s : s) -> per-wave
// quad sums equalize (the per-round barrier waits on the heaviest wave).
__global__ __launch_bounds__(256) void meta_kernel(const int* __restrict__ ei,
                                                   int* __restrict__ perm, int* __restrict__ invperm,
                                                   float* __restrict__ wvslot, int* __restrict__ gmaxq,
                                                   int* __restrict__ cursor) {
    __shared__ int outc[NN];
    __shared__ int indc[NN];
    __shared__ int hist[MAXD + 2];
    __shared__ int start[MAXD + 2];
    int tid = threadIdx.x;
#pragma unroll
    for (int l = 0; l < 8; ++l) {
        int j = tid + (l << 8);
        outc[j] = 0;
        indc[j] = 0;
        cursor[j] = 0;  // for fill_kernel
    }
    if (tid < MAXD + 2) hist[tid] = 0;
    __syncthreads();
    for (int e = tid; e < NE; e += 256) {  // coalesced edge pass; LDS atomics
        atomicAdd(&outc[ei[e]], 1);
        atomicAdd(&indc[ei[NE + e]], 1);
    }
    __syncthreads();
#pragma unroll
    for (int l = 0; l < 8; ++l) {
        int j = tid + (l << 8);
        atomicAdd(&hist[min(indc[j], MAXD)], 1);
    }
    __syncthreads();
    if (tid == 0) {
        int s = 0;
        for (int k = 0; k <= MAXD; ++k) { start[k] = s; s += hist[k]; }
    }
    __syncthreads();
#pragma unroll
    for (int l = 0; l < 8; ++l) {
        int j = tid + (l << 8);
        int t = atomicAdd(&start[min(indc[j], MAXD)], 1);  // sorted rank
        int q = t >> 9;                                    // stratum (0..3)
        int s = (t >> 6) & 7;                              // group within stratum
        int sp = (q & 1) ? (7 - s) : s;                    // snake
        int slot = (((q << 3) + sp) << 6) | (t & 63);
        perm[slot] = j;
        invperm[j] = slot;
    }
    __threadfence();
    __syncthreads();  // perm[] (global) fully written & visible before cross-thread reads below
#pragma unroll
    for (int l = 0; l < 8; ++l) {
        int t = tid + (l << 8);
        int c = outc[perm[t]];
        wvslot[t] = c ? 0.5f / (float)c : 0.0f;  // deg==0 row spreads nothing
    }
    if (tid < 32) {
        int m = 0;
        for (int k = 0; k < 64; ++k) m = max(m, indc[perm[tid * 64 + k]]);
        m = min(m, MAXD);
        gmaxq[tid] = (m + 3) >> 2;
    }
}

// ---------------- fill: transposed (CSC) quad-packed table in SLOT coordinates ----------------
// Quad-level q of dest-slot sd at uint2 index q*NN + sd; halfwords hold source SLOT ids.
// Slot p: word = (p>>2)*(NN*2) + sd*2 + ((p>>1)&1), halfword = p&1. And+Or race only with
// the other half of the same word (disjoint masks) -> safe.
__global__ __launch_bounds__(256) void fill_kernel(const int* __restrict__ ei, const int* __restrict__ invperm,
                                                   int* __restrict__ cursor, unsigned* __restrict__ T) {
    int e = blockIdx.x * 256 + threadIdx.x;
    if (e >= NE) return;
    int s = ei[e];
    int d = ei[NE + e];
    int p = atomicAdd(&cursor[d], 1);
    if (p < MAXD) {
        int sd = invperm[d];
        int wi = (p >> 2) * (NN * 2) + sd * 2 + ((p >> 1) & 1);
        int sh = (p & 1) * 16;
        atomicAnd(&T[wi], ~(0xFFFFu << sh));
        atomicOr(&T[wi], ((unsigned)invperm[s]) << sh);
    }
}

// ---------------- 4-source local push + key-based top-20 + FUSED output epilogue ----------------
// BYTE-IDENTICAL to the round-10 kernel (proven 460 us total incl. epilogue, 120 VGPR,
// loads in flight; rounds 6/8 proved inner-loop edits collapse codegen to ~52 VGPR
// serialized reads). Tripwire: VGPR must stay 120.
__global__ __launch_bounds__(512, 2) void push_topk_kernel(const unsigned* __restrict__ Tw,
                                                           const float* __restrict__ wvslotg,
                                                           const int* __restrict__ gmaxqg,
                                                           const int* __restrict__ permg,
                                                           const int* __restrict__ invpermg,
                                                           const float* __restrict__ feats,
                                                           float* __restrict__ outg) {
    __shared__ f32x4 PVbuf[2 * (NN + 1)];  // [parity][slot]; [*][NN] = zero sentinel
    __shared__ int swf[2][8];              // [parity][wave] convergence flags
    __shared__ float twv[NSRC][TOPK];      // fused-epilogue weights
    __shared__ int twi[NSRC][TOPK];        // fused-epilogue indices (original node ids)

    const int tid = threadIdx.x;
    const int lane = tid & 63;
    const int wvid = tid >> 6;  // 0..7
    const int s0 = blockIdx.x * NSRC;
    const uint2* Tq = (const uint2*)Tw;
    const f32x4 z = {0.f, 0.f, 0.f, 0.f};

    f32x4 Rr[NL], Pr[NL];
    float wvv[NL];
    int gql[NL];  // wave-uniform in-degree bounds -> SGPRs (group of j=tid+l*512 is wvid+8l)
#pragma unroll
    for (int l = 0; l < NL; ++l) gql[l] = __builtin_amdgcn_readfirstlane(gmaxqg[wvid + (l << 3)]);

#pragma unroll
    for (int l = 0; l < NL; ++l) {
        int j = tid + (l << 9);
        Rr[l] = z;
        Pr[l] = z;
        wvv[l] = wvslotg[j];
        PVbuf[j] = z;  // buffer 0; buffer 1 fully written in round 0 before round 1 reads it
    }
    if (tid == 0) { PVbuf[NN] = z; PVbuf[2 * NN + 1] = z; }  // both sentinels, never rewritten
    // fold reference round 1 (only the source is >= RMAX): P[s][c]=0.5, PV0[slot(s)][c]=winv05[s]
    int srcslot[NSRC];
#pragma unroll
    for (int c = 0; c < NSRC; ++c) srcslot[c] = invpermg[s0 + c];
#pragma unroll
    for (int l = 0; l < NL; ++l) {
        int j = tid + (l << 9);
#pragma unroll
        for (int c = 0; c < NSRC; ++c) {
            if (j == srcslot[c]) {
                Pr[l][c] = 0.5f;
                ((float*)&PVbuf[j])[c] = wvv[l];  // compile-time c -> single ds_write_b32
            }
        }
    }
    __syncthreads();

    int flagreg = 1;
    for (int round = 0; flagreg && round < MAXROUNDS; ++round) {
        const int p = round & 1;
        const f32x4* PVc = PVbuf + p * (NN + 1);  // read buffer
        f32x4* PVn = PVbuf + (p ^ 1) * (NN + 1);  // write buffer
        bool above = false;
#pragma unroll
        for (int l = 0; l < NL; ++l) {
            int j = tid + (l << 9);
            const uint2* colq = Tq + j;
            int gq = gql[l];
            f32x4 d = z;
#pragma unroll 2
            for (int q = 0; q < gq; ++q) {
                uint2 w = colq[q * NN];  // coalesced 512B/wave, L2-resident
                d += PVc[w.x & 0xFFFFu];
                d += PVc[w.x >> 16];
                d += PVc[w.y & 0xFFFFu];
                d += PVc[w.y >> 16];
            }
            f32x4 rn = Rr[l] + d;
            f32x4 pv;
#pragma unroll
            for (int u = 0; u < 4; ++u) {
                float r = rn[u];
                if (r >= RMAXF) {
                    Pr[l][u] += 0.5f * r;
                    pv[u] = r * wvv[l];
                    rn[u] = 0.0f;
                    above = true;
                } else {
                    pv[u] = 0.0f;
                }
            }
            PVn[j] = pv;
            Rr[l] = rn;
        }
        int anyv = __any(above) ? 1 : 0;     // all lanes participate
        if (lane == 0) swf[p][wvid] = anyv;  // unconditional write -> no reset needed
        __syncthreads();                     // PVn writes + flags visible; PVc reads done
        flagreg = swf[p][0] | swf[p][1] | swf[p][2] | swf[p][3] |
                  swf[p][4] | swf[p][5] | swf[p][6] | swf[p][7];
    }

    // ---- top-20 via u64 keys (permutation-invariant): key = (float_bits(P)<<32) | ~id ----
    // P >= 0 -> float-bit order == value order; ~id -> lowest original id on value ties
    // (matches stable lax.top_k). Keys live in the dead PV buffer (4 sources x 2048 x 8B).
    u64* K = (u64*)PVbuf;
#pragma unroll
    for (int l = 0; l < NL; ++l) {
        int j = tid + (l << 9);
        unsigned nid = ~(unsigned)permg[j];
#pragma unroll
        for (int c = 0; c < NSRC; ++c)
            K[c * NN + j] = ((u64)__float_as_uint(Pr[l][c]) << 32) | nid;
    }
    __syncthreads();

    const int w = wvid;  // wave id == source component; waves scan disjoint key arrays
    if (w < NSRC) {
        u64* Kw = K + w * NN;
        u64 bk = 0;
        int bs = 0;
#pragma unroll
        for (int k = 0; k < 32; ++k) {
            int n = lane + (k << 6);
            u64 kk = Kw[n];
            if (kk > bk) { bk = kk; bs = n; }
        }
        for (int s = 0; s < TOPK; ++s) {
            u64 mk = bk;
#pragma unroll
            for (int off = 32; off > 0; off >>= 1) {  // butterfly max (keys unique: ids distinct)
                u64 ok = __shfl_xor(mk, off, 64);
                if (ok > mk) mk = ok;
            }
            if (lane == 0) {
                twv[w][s] = __uint_as_float((unsigned)(mk >> 32));
                twi[w][s] = (int)(~(unsigned)mk);
            }
            if (bk == mk) {  // unique owner pops winner, rescans its 32 slots
                Kw[bs] = 0;  // 0 < every real key (low word ~id > 0)
                bk = 0;
                bs = 0;
#pragma unroll
                for (int k = 0; k < 32; ++k) {
                    int n = lane + (k << 6);
                    u64 kk = Kw[n];
                    if (kk > bk) { bk = kk; bs = n; }
                }
            }
        }
    }
    __syncthreads();  // twv/twi visible to all waves

    // ---- fused epilogue: out[s0+row] = sum_v w_v * feats[idx_v]  (128 threads per row) ----
    {
        const int row = tid >> 7;          // 0..3
        const int c0 = (tid & 127) << 4;   // 16 floats per thread
        f32x4 a0 = z, a1 = z, a2 = z, a3 = z;
        for (int v = 0; v < TOPK; ++v) {
            float w8 = twv[row][v];
            const f32x4* fr = (const f32x4*)(feats + (size_t)twi[row][v] * DF + c0);
            a0 += w8 * fr[0];
            a1 += w8 * fr[1];
            a2 += w8 * fr[2];
            a3 += w8 * fr[3];
        }
        f32x4* op = (f32x4*)(outg + (size_t)(s0 + row) * DF + c0);
        op[0] = a0;
        op[1] = a1;
        op[2] = a2;
        op[3] = a3;
    }
}

extern "C" void kernel_launch(void* const* d_in, const int* in_sizes, int n_in,
                              void* d_out, int out_size, void* d_ws, size_t ws_size,
                              hipStream_t stream) {
    const float* feats = (const float*)d_in[0];
    const int* ei = (const int*)d_in[1];
    float* out = (float*)d_out;

    int* cursor = (int*)d_ws;                     // 2048
    int* perm = cursor + NN;                      // 2048 (slot -> node id)
    int* invperm = perm + NN;                     // 2048 (node id -> slot)
    float* wvslot = (float*)(invperm + NN);       // 2048 (0.5/outdeg by slot)
    int* gmaxq = (int*)(wvslot + NN);             // 64 (32 used; keeps T 8B-aligned)
    unsigned* T = (unsigned*)(gmaxq + 64);        // 12*2048*2 words (quad-packed CSC, slot ids)

    init_kernel<<<(MAXDQ * NN * 2 + 255) / 256, 256, 0, stream>>>(T);
    meta_kernel<<<1, 256, 0, stream>>>(ei, perm, invperm, wvslot, gmaxq, cursor);
    fill_kernel<<<(NE + 255) / 256, 256, 0, stream>>>(ei, invperm, cursor, T);
    push_topk_kernel<<<NN / NSRC, 512, 0, stream>>>(T, wvslot, gmaxq, perm, invperm, feats, out);
}

// Round 12
// 518.210 us; speedup vs baseline: 1.1055x; 1.1055x over previous
//
#include <hip/hip_runtime.h>

#define NN 2048
#define NE 32768
#define DF 2048
#define TOPK 20
#define RMAXF 1e-5f
#define MAXD 48           // supported max in-degree (Poisson(16); verified by passing rounds)
#define MAXDQ (MAXD / 4)  // 12 quad-levels of 4 packed edges
#define SENTW 0x08000800u // two packed sentinel slot-ids (2048 -> PV[2048] == 0)
#define NSRC 4            // sources per block (float4-packed PV)
#define MAXROUNDS 64      // safety cap; provably unreachable (mass halves/round)
#define NL 4              // owned slots per thread (512 threads)

typedef __attribute__((ext_vector_type(4))) float f32x4;
typedef unsigned long long u64;

// ---------------- init: zero counters, sentinel-fill transposed in-edge table ----------------
__global__ __launch_bounds__(256) void init_kernel(int* __restrict__ outcnt, int* __restrict__ indeg,
                                                   unsigned* __restrict__ T) {
    int i = blockIdx.x * 256 + threadIdx.x;
    if (i < MAXDQ * NN * 2) T[i] = SENTW;
    if (i < NN) { outcnt[i] = 0; indeg[i] = 0; }
}

// ---------------- count: out-degree and in-degree (parallel pass; round-11 proved fusing
// this into the single-block meta costs ~60 us of serialization) ----------------
__global__ __launch_bounds__(256) void count_kernel(const int* __restrict__ ei, int* __restrict__ outcnt,
                                                    int* __restrict__ indeg) {
    int e = blockIdx.x * 256 + threadIdx.x;
    if (e >= NE) return;
    atomicAdd(&outcnt[ei[e]], 1);
    atomicAdd(&indeg[ei[NE + e]], 1);
}

// ---------------- meta: degree-sorted slots with SNAKE group placement ----------------
// Counting sort by in-degree (round-7 win: wave-uniform gather bound ~= local mean).
// Snake placement (round-10 win): sorted rank t -> stratum q = t>>9, within-stratum group
// s = (t>>6)&7, physical group = q*8 + (q odd ? 7-s : s). Wave w owns physical groups
// {q*8+w}, so its quad total becomes sum_q gq(q, w or 7-w) -> per-wave sums equalize
// (the per-round barrier waits on the heaviest wave).
__global__ __launch_bounds__(256) void meta_kernel(const int* __restrict__ outcnt, const int* __restrict__ indeg,
                                                   int* __restrict__ perm, int* __restrict__ invperm,
                                                   float* __restrict__ wvslot, int* __restrict__ gmaxq,
                                                   int* __restrict__ cursor) {
    __shared__ int hist[MAXD + 2];
    __shared__ int start[MAXD + 2];
    int tid = threadIdx.x;
    if (tid < MAXD + 2) hist[tid] = 0;
    __syncthreads();
#pragma unroll
    for (int l = 0; l < 8; ++l) {
        int j = tid + (l << 8);
        atomicAdd(&hist[min(indeg[j], MAXD)], 1);
        cursor[j] = 0;
    }
    __syncthreads();
    if (tid == 0) {
        int s = 0;
        for (int k = 0; k <= MAXD; ++k) { start[k] = s; s += hist[k]; }
    }
    __syncthreads();
#pragma unroll
    for (int l = 0; l < 8; ++l) {
        int j = tid + (l << 8);
        int t = atomicAdd(&start[min(indeg[j], MAXD)], 1);  // sorted rank
        int q = t >> 9;                                     // stratum (0..3)
        int s = (t >> 6) & 7;                               // group within stratum
        int sp = (q & 1) ? (7 - s) : s;                     // snake
        int slot = (((q << 3) + sp) << 6) | (t & 63);
        perm[slot] = j;
        invperm[j] = slot;
    }
    __threadfence();
    __syncthreads();  // perm[] fully written & visible before cross-thread reads below
#pragma unroll
    for (int l = 0; l < 8; ++l) {
        int t = tid + (l << 8);
        int c = outcnt[perm[t]];
        wvslot[t] = c ? 0.5f / (float)c : 0.0f;  // deg==0 row spreads nothing
    }
    if (tid < 32) {
        int m = 0;
        for (int k = 0; k < 64; ++k) m = max(m, indeg[perm[tid * 64 + k]]);
        m = min(m, MAXD);
        gmaxq[tid] = (m + 3) >> 2;
    }
}

// ---------------- fill: transposed (CSC) quad-packed table in SLOT coordinates ----------------
// Quad-level q of dest-slot sd at uint2 index q*NN + sd; halfword index = word*2 + (p&1).
// Each halfword has exactly ONE writer (unique cursor slot per edge), and gfx950 sub-dword
// stores are byte-enabled through L2 (no word RMW) -> plain 2-byte store replaces the
// round-10 atomicAnd+atomicOr pair.
__global__ __launch_bounds__(256) void fill_kernel(const int* __restrict__ ei, const int* __restrict__ invperm,
                                                   int* __restrict__ cursor, unsigned short* __restrict__ T16) {
    int e = blockIdx.x * 256 + threadIdx.x;
    if (e >= NE) return;
    int s = ei[e];
    int d = ei[NE + e];
    int p = atomicAdd(&cursor[d], 1);
    if (p < MAXD) {
        int sd = invperm[d];
        int wi = (p >> 2) * (NN * 2) + sd * 2 + ((p >> 1) & 1);  // 32-bit word index
        T16[wi * 2 + (p & 1)] = (unsigned short)invperm[s];
    }
}

// ---------------- 4-source local push + key-based top-20 + FUSED output epilogue ----------------
// BYTE-IDENTICAL to the round-10 kernel (best measured: 460 us incl. epilogue, 120 VGPR,
// loads in flight; rounds 6/8 proved inner-loop edits collapse codegen to ~52 VGPR
// serialized reads). Tripwire: VGPR must stay 120, LDS 66560, conflicts ~5.7e7.
__global__ __launch_bounds__(512, 2) void push_topk_kernel(const unsigned* __restrict__ Tw,
                                                           const float* __restrict__ wvslotg,
                                                           const int* __restrict__ gmaxqg,
                                                           const int* __restrict__ permg,
                                                           const int* __restrict__ invpermg,
                                                           const float* __restrict__ feats,
                                                           float* __restrict__ outg) {
    __shared__ f32x4 PVbuf[2 * (NN + 1)];  // [parity][slot]; [*][NN] = zero sentinel
    __shared__ int swf[2][8];              // [parity][wave] convergence flags
    __shared__ float twv[NSRC][TOPK];      // fused-epilogue weights
    __shared__ int twi[NSRC][TOPK];        // fused-epilogue indices (original node ids)

    const int tid = threadIdx.x;
    const int lane = tid & 63;
    const int wvid = tid >> 6;  // 0..7
    const int s0 = blockIdx.x * NSRC;
    const uint2* Tq = (const uint2*)Tw;
    const f32x4 z = {0.f, 0.f, 0.f, 0.f};

    f32x4 Rr[NL], Pr[NL];
    float wvv[NL];
    int gql[NL];  // wave-uniform in-degree bounds -> SGPRs (group of j=tid+l*512 is wvid+8l)
#pragma unroll
    for (int l = 0; l < NL; ++l) gql[l] = __builtin_amdgcn_readfirstlane(gmaxqg[wvid + (l << 3)]);

#pragma unroll
    for (int l = 0; l < NL; ++l) {
        int j = tid + (l << 9);
        Rr[l] = z;
        Pr[l] = z;
        wvv[l] = wvslotg[j];
        PVbuf[j] = z;  // buffer 0; buffer 1 fully written in round 0 before round 1 reads it
    }
    if (tid == 0) { PVbuf[NN] = z; PVbuf[2 * NN + 1] = z; }  // both sentinels, never rewritten
    // fold reference round 1 (only the source is >= RMAX): P[s][c]=0.5, PV0[slot(s)][c]=winv05[s]
    int srcslot[NSRC];
#pragma unroll
    for (int c = 0; c < NSRC; ++c) srcslot[c] = invpermg[s0 + c];
#pragma unroll
    for (int l = 0; l < NL; ++l) {
        int j = tid + (l << 9);
#pragma unroll
        for (int c = 0; c < NSRC; ++c) {
            if (j == srcslot[c]) {
                Pr[l][c] = 0.5f;
                ((float*)&PVbuf[j])[c] = wvv[l];  // compile-time c -> single ds_write_b32
            }
        }
    }
    __syncthreads();

    int flagreg = 1;
    for (int round = 0; flagreg && round < MAXROUNDS; ++round) {
        const int p = round & 1;
        const f32x4* PVc = PVbuf + p * (NN + 1);  // read buffer
        f32x4* PVn = PVbuf + (p ^ 1) * (NN + 1);  // write buffer
        bool above = false;
#pragma unroll
        for (int l = 0; l < NL; ++l) {
            int j = tid + (l << 9);
            const uint2* colq = Tq + j;
            int gq = gql[l];
            f32x4 d = z;
#pragma unroll 2
            for (int q = 0; q < gq; ++q) {
                uint2 w = colq[q * NN];  // coalesced 512B/wave, L2-resident
                d += PVc[w.x & 0xFFFFu];
                d += PVc[w.x >> 16];
                d += PVc[w.y & 0xFFFFu];
                d += PVc[w.y >> 16];
            }
            f32x4 rn = Rr[l] + d;
            f32x4 pv;
#pragma unroll
            for (int u = 0; u < 4; ++u) {
                float r = rn[u];
                if (r >= RMAXF) {
                    Pr[l][u] += 0.5f * r;
                    pv[u] = r * wvv[l];
                    rn[u] = 0.0f;
                    above = true;
                } else {
                    pv[u] = 0.0f;
                }
            }
            PVn[j] = pv;
            Rr[l] = rn;
        }
        int anyv = __any(above) ? 1 : 0;     // all lanes participate
        if (lane == 0) swf[p][wvid] = anyv;  // unconditional write -> no reset needed
        __syncthreads();                     // PVn writes + flags visible; PVc reads done
        flagreg = swf[p][0] | swf[p][1] | swf[p][2] | swf[p][3] |
                  swf[p][4] | swf[p][5] | swf[p][6] | swf[p][7];
    }

    // ---- top-20 via u64 keys (permutation-invariant): key = (float_bits(P)<<32) | ~id ----
    // P >= 0 -> float-bit order == value order; ~id -> lowest original id on value ties
    // (matches stable lax.top_k). Keys live in the dead PV buffer (4 sources x 2048 x 8B).
    u64* K = (u64*)PVbuf;
#pragma unroll
    for (int l = 0; l < NL; ++l) {
        int j = tid + (l << 9);
        unsigned nid = ~(unsigned)permg[j];
#pragma unroll
        for (int c = 0; c < NSRC; ++c)
            K[c * NN + j] = ((u64)__float_as_uint(Pr[l][c]) << 32) | nid;
    }
    __syncthreads();

    const int w = wvid;  // wave id == source component; waves scan disjoint key arrays
    if (w < NSRC) {
        u64* Kw = K + w * NN;
        u64 bk = 0;
        int bs = 0;
#pragma unroll
        for (int k = 0; k < 32; ++k) {
            int n = lane + (k << 6);
            u64 kk = Kw[n];
            if (kk > bk) { bk = kk; bs = n; }
        }
        for (int s = 0; s < TOPK; ++s) {
            u64 mk = bk;
#pragma unroll
            for (int off = 32; off > 0; off >>= 1) {  // butterfly max (keys unique: ids distinct)
                u64 ok = __shfl_xor(mk, off, 64);
                if (ok > mk) mk = ok;
            }
            if (lane == 0) {
                twv[w][s] = __uint_as_float((unsigned)(mk >> 32));
                twi[w][s] = (int)(~(unsigned)mk);
            }
            if (bk == mk) {  // unique owner pops winner, rescans its 32 slots
                Kw[bs] = 0;  // 0 < every real key (low word ~id > 0)
                bk = 0;
                bs = 0;
#pragma unroll
                for (int k = 0; k < 32; ++k) {
                    int n = lane + (k << 6);
                    u64 kk = Kw[n];
                    if (kk > bk) { bk = kk; bs = n; }
                }
            }
        }
    }
    __syncthreads();  // twv/twi visible to all waves

    // ---- fused epilogue: out[s0+row] = sum_v w_v * feats[idx_v]  (128 threads per row) ----
    {
        const int row = tid >> 7;          // 0..3
        const int c0 = (tid & 127) << 4;   // 16 floats per thread
        f32x4 a0 = z, a1 = z, a2 = z, a3 = z;
        for (int v = 0; v < TOPK; ++v) {
            float w8 = twv[row][v];
            const f32x4* fr = (const f32x4*)(feats + (size_t)twi[row][v] * DF + c0);
            a0 += w8 * fr[0];
            a1 += w8 * fr[1];
            a2 += w8 * fr[2];
            a3 += w8 * fr[3];
        }
        f32x4* op = (f32x4*)(outg + (size_t)(s0 + row) * DF + c0);
        op[0] = a0;
        op[1] = a1;
        op[2] = a2;
        op[3] = a3;
    }
}

extern "C" void kernel_launch(void* const* d_in, const int* in_sizes, int n_in,
                              void* d_out, int out_size, void* d_ws, size_t ws_size,
                              hipStream_t stream) {
    const float* feats = (const float*)d_in[0];
    const int* ei = (const int*)d_in[1];
    float* out = (float*)d_out;

    int* outcnt = (int*)d_ws;                     // 2048
    int* indeg = outcnt + NN;                     // 2048
    int* cursor = indeg + NN;                     // 2048
    int* perm = cursor + NN;                      // 2048 (slot -> node id)
    int* invperm = perm + NN;                     // 2048 (node id -> slot)
    float* wvslot = (float*)(invperm + NN);       // 2048 (0.5/outdeg by slot)
    int* gmaxq = (int*)(wvslot + NN);             // 64 (32 used; keeps T 8B-aligned)
    unsigned* T = (unsigned*)(gmaxq + 64);        // 12*2048*2 words (quad-packed CSC, slot ids)

    init_kernel<<<(MAXDQ * NN * 2 + 255) / 256, 256, 0, stream>>>(outcnt, indeg, T);
    count_kernel<<<(NE + 255) / 256, 256, 0, stream>>>(ei, outcnt, indeg);
    meta_kernel<<<1, 256, 0, stream>>>(outcnt, indeg, perm, invperm, wvslot, gmaxq, cursor);
    fill_kernel<<<(NE + 255) / 256, 256, 0, stream>>>(ei, invperm, cursor, (unsigned short*)T);
    push_topk_kernel<<<NN / NSRC, 512, 0, stream>>>(T, wvslot, gmaxq, perm, invperm, feats, out);
}

// Round 14
// 515.926 us; speedup vs baseline: 1.1104x; 1.0044x over previous
//
#include <hip/hip_runtime.h>

#define NN 2048
#define NE 32768
#define DF 2048
#define TOPK 20
#define RMAXF 1e-5f
#define MAXD 48           // supported max in-degree (Poisson(16); verified by passing rounds)
#define MAXDQ (MAXD / 4)  // 12 quad-levels of 4 packed edges
#define SENTW 0x08000800u // two packed sentinel slot-ids (2048 -> PV[2048] == 0)
#define NSRC 4            // sources per block (float4-packed PV)
#define MAXROUNDS 64      // safety cap; provably unreachable (mass halves/round)
#define NL 4              // owned slots per thread (512 threads)

typedef __attribute__((ext_vector_type(4))) float f32x4;
typedef unsigned long long u64;

// ---------------- init: zero counters, sentinel-fill transposed in-edge table ----------------
__global__ __launch_bounds__(256) void init_kernel(int* __restrict__ outcnt, int* __restrict__ indeg,
                                                   unsigned* __restrict__ T) {
    int i = blockIdx.x * 256 + threadIdx.x;
    if (i < MAXDQ * NN * 2) T[i] = SENTW;
    if (i < NN) { outcnt[i] = 0; indeg[i] = 0; }
}

// ---------------- count: out-degree and in-degree (parallel pass; round-11 proved fusing
// this into the single-block meta costs ~60 us of serialization) ----------------
__global__ __launch_bounds__(256) void count_kernel(const int* __restrict__ ei, int* __restrict__ outcnt,
                                                    int* __restrict__ indeg) {
    int e = blockIdx.x * 256 + threadIdx.x;
    if (e >= NE) return;
    atomicAdd(&outcnt[ei[e]], 1);
    atomicAdd(&indeg[ei[NE + e]], 1);
}

// ---------------- meta: degree-sorted slots with SNAKE group placement ----------------
// Counting sort by in-degree (round-7 win: wave-uniform gather bound ~= local mean).
// Snake placement (round-10 win): sorted rank t -> stratum q = t>>9, within-stratum group
// s = (t>>6)&7, physical group = q*8 + (q odd ? 7-s : s) -> per-wave quad sums equalize
// (the per-round barrier waits on the heaviest wave).
__global__ __launch_bounds__(256) void meta_kernel(const int* __restrict__ outcnt, const int* __restrict__ indeg,
                                                   int* __restrict__ perm, int* __restrict__ invperm,
                                                   float* __restrict__ wvslot, int* __restrict__ gmaxq,
                                                   int* __restrict__ cursor) {
    __shared__ int hist[MAXD + 2];
    __shared__ int start[MAXD + 2];
    int tid = threadIdx.x;
    if (tid < MAXD + 2) hist[tid] = 0;
    __syncthreads();
#pragma unroll
    for (int l = 0; l < 8; ++l) {
        int j = tid + (l << 8);
        atomicAdd(&hist[min(indeg[j], MAXD)], 1);
        cursor[j] = 0;
    }
    __syncthreads();
    if (tid == 0) {
        int s = 0;
        for (int k = 0; k <= MAXD; ++k) { start[k] = s; s += hist[k]; }
    }
    __syncthreads();
#pragma unroll
    for (int l = 0; l < 8; ++l) {
        int j = tid + (l << 8);
        int t = atomicAdd(&start[min(indeg[j], MAXD)], 1);  // sorted rank
        int q = t >> 9;                                     // stratum (0..3)
        int s = (t >> 6) & 7;                               // group within stratum
        int sp = (q & 1) ? (7 - s) : s;                     // snake
        int slot = (((q << 3) + sp) << 6) | (t & 63);
        perm[slot] = j;
        invperm[j] = slot;
    }
    __threadfence();
    __syncthreads();  // perm[] fully written & visible before cross-thread reads below
#pragma unroll
    for (int l = 0; l < 8; ++l) {
        int t = tid + (l << 8);
        int c = outcnt[perm[t]];
        wvslot[t] = c ? 0.5f / (float)c : 0.0f;  // deg==0 row spreads nothing
    }
    if (tid < 32) {
        int m = 0;
        for (int k = 0; k < 64; ++k) m = max(m, indeg[perm[tid * 64 + k]]);
        m = min(m, MAXD);
        gmaxq[tid] = (m + 3) >> 2;
    }
}

// ---------------- fill: transposed (CSC) quad-packed table in SLOT coordinates ----------------
// Each halfword has exactly ONE writer (unique cursor slot per edge); gfx950 sub-dword
// stores are byte-enabled through L2 -> plain 2-byte store (round-12 win vs atomic pair).
__global__ __launch_bounds__(256) void fill_kernel(const int* __restrict__ ei, const int* __restrict__ invperm,
                                                   int* __restrict__ cursor, unsigned short* __restrict__ T16) {
    int e = blockIdx.x * 256 + threadIdx.x;
    if (e >= NE) return;
    int s = ei[e];
    int d = ei[NE + e];
    int p = atomicAdd(&cursor[d], 1);
    if (p < MAXD) {
        int sd = invperm[d];
        int wi = (p >> 2) * (NN * 2) + sd * 2 + ((p >> 1) & 1);  // 32-bit word index
        T16[wi * 2 + (p & 1)] = (unsigned short)invperm[s];
    }
}

// ---------------- 4-source local push + key-based top-20 + FUSED output epilogue ----------------
// SINGLE-VARIABLE EXPERIMENT vs the proven round-12 kernel (resubmit of round 13 -- infra
// failure, no verdict): the gather accumulator is split d -> d0/d1 (alternating edges,
// joined after the loop). Halves the serial ds_read->add dependency chain (the measured
// stall residue: LDS pipe ~25%, VALU ~39%, neither saturated at 16 waves/CU).
// Everything else byte-identical.
// Tripwires: VGPR must stay in [100,128]. ~52 => dual-acc IS the rounds-6/8 collapse
// trigger, revert. >128 => 16-wave -> 8-wave occupancy cliff, revert.
__global__ __launch_bounds__(512, 2) void push_topk_kernel(const unsigned* __restrict__ Tw,
                                                           const float* __restrict__ wvslotg,
                                                           const int* __restrict__ gmaxqg,
                                                           const int* __restrict__ permg,
                                                           const int* __restrict__ invpermg,
                                                           const float* __restrict__ feats,
                                                           float* __restrict__ outg) {
    __shared__ f32x4 PVbuf[2 * (NN + 1)];  // [parity][slot]; [*][NN] = zero sentinel
    __shared__ int swf[2][8];              // [parity][wave] convergence flags
    __shared__ float twv[NSRC][TOPK];      // fused-epilogue weights
    __shared__ int twi[NSRC][TOPK];        // fused-epilogue indices (original node ids)

    const int tid = threadIdx.x;
    const int lane = tid & 63;
    const int wvid = tid >> 6;  // 0..7
    const int s0 = blockIdx.x * NSRC;
    const uint2* Tq = (const uint2*)Tw;
    const f32x4 z = {0.f, 0.f, 0.f, 0.f};

    f32x4 Rr[NL], Pr[NL];
    float wvv[NL];
    int gql[NL];  // wave-uniform in-degree bounds -> SGPRs (group of j=tid+l*512 is wvid+8l)
#pragma unroll
    for (int l = 0; l < NL; ++l) gql[l] = __builtin_amdgcn_readfirstlane(gmaxqg[wvid + (l << 3)]);

#pragma unroll
    for (int l = 0; l < NL; ++l) {
        int j = tid + (l << 9);
        Rr[l] = z;
        Pr[l] = z;
        wvv[l] = wvslotg[j];
        PVbuf[j] = z;  // buffer 0; buffer 1 fully written in round 0 before round 1 reads it
    }
    if (tid == 0) { PVbuf[NN] = z; PVbuf[2 * NN + 1] = z; }  // both sentinels, never rewritten
    // fold reference round 1 (only the source is >= RMAX): P[s][c]=0.5, PV0[slot(s)][c]=winv05[s]
    int srcslot[NSRC];
#pragma unroll
    for (int c = 0; c < NSRC; ++c) srcslot[c] = invpermg[s0 + c];
#pragma unroll
    for (int l = 0; l < NL; ++l) {
        int j = tid + (l << 9);
#pragma unroll
        for (int c = 0; c < NSRC; ++c) {
            if (j == srcslot[c]) {
                Pr[l][c] = 0.5f;
                ((float*)&PVbuf[j])[c] = wvv[l];  // compile-time c -> single ds_write_b32
            }
        }
    }
    __syncthreads();

    int flagreg = 1;
    for (int round = 0; flagreg && round < MAXROUNDS; ++round) {
        const int p = round & 1;
        const f32x4* PVc = PVbuf + p * (NN + 1);  // read buffer
        f32x4* PVn = PVbuf + (p ^ 1) * (NN + 1);  // write buffer
        bool above = false;
#pragma unroll
        for (int l = 0; l < NL; ++l) {
            int j = tid + (l << 9);
            const uint2* colq = Tq + j;
            int gq = gql[l];
            f32x4 d0 = z, d1 = z;  // dual chains: the single isolated change this round
#pragma unroll 2
            for (int q = 0; q < gq; ++q) {
                uint2 w = colq[q * NN];  // coalesced 512B/wave, L2-resident
                d0 += PVc[w.x & 0xFFFFu];
                d1 += PVc[w.x >> 16];
                d0 += PVc[w.y & 0xFFFFu];
                d1 += PVc[w.y >> 16];
            }
            f32x4 rn = Rr[l] + (d0 + d1);
            f32x4 pv;
#pragma unroll
            for (int u = 0; u < 4; ++u) {
                float r = rn[u];
                if (r >= RMAXF) {
                    Pr[l][u] += 0.5f * r;
                    pv[u] = r * wvv[l];
                    rn[u] = 0.0f;
                    above = true;
                } else {
                    pv[u] = 0.0f;
                }
            }
            PVn[j] = pv;
            Rr[l] = rn;
        }
        int anyv = __any(above) ? 1 : 0;     // all lanes participate
        if (lane == 0) swf[p][wvid] = anyv;  // unconditional write -> no reset needed
        __syncthreads();                     // PVn writes + flags visible; PVc reads done
        flagreg = swf[p][0] | swf[p][1] | swf[p][2] | swf[p][3] |
                  swf[p][4] | swf[p][5] | swf[p][6] | swf[p][7];
    }

    // ---- top-20 via u64 keys (permutation-invariant): key = (float_bits(P)<<32) | ~id ----
    // P >= 0 -> float-bit order == value order; ~id -> lowest original id on value ties
    // (matches stable lax.top_k). Keys live in the dead PV buffer (4 sources x 2048 x 8B).
    u64* K = (u64*)PVbuf;
#pragma unroll
    for (int l = 0; l < NL; ++l) {
        int j = tid + (l << 9);
        unsigned nid = ~(unsigned)permg[j];
#pragma unroll
        for (int c = 0; c < NSRC; ++c)
            K[c * NN + j] = ((u64)__float_as_uint(Pr[l][c]) << 32) | nid;
    }
    __syncthreads();

    const int w = wvid;  // wave id == source component; waves scan disjoint key arrays
    if (w < NSRC) {
        u64* Kw = K + w * NN;
        u64 bk = 0;
        int bs = 0;
#pragma unroll
        for (int k = 0; k < 32; ++k) {
            int n = lane + (k << 6);
            u64 kk = Kw[n];
            if (kk > bk) { bk = kk; bs = n; }
        }
        for (int s = 0; s < TOPK; ++s) {
            u64 mk = bk;
#pragma unroll
            for (int off = 32; off > 0; off >>= 1) {  // butterfly max (keys unique: ids distinct)
                u64 ok = __shfl_xor(mk, off, 64);
                if (ok > mk) mk = ok;
            }
            if (lane == 0) {
                twv[w][s] = __uint_as_float((unsigned)(mk >> 32));
                twi[w][s] = (int)(~(unsigned)mk);
            }
            if (bk == mk) {  // unique owner pops winner, rescans its 32 slots
                Kw[bs] = 0;  // 0 < every real key (low word ~id > 0)
                bk = 0;
                bs = 0;
#pragma unroll
                for (int k = 0; k < 32; ++k) {
                    int n = lane + (k << 6);
                    u64 kk = Kw[n];
                    if (kk > bk) { bk = kk; bs = n; }
                }
            }
        }
    }
    __syncthreads();  // twv/twi visible to all waves

    // ---- fused epilogue: out[s0+row] = sum_v w_v * feats[idx_v]  (128 threads per row) ----
    {
        const int row = tid >> 7;          // 0..3
        const int c0 = (tid & 127) << 4;   // 16 floats per thread
        f32x4 a0 = z, a1 = z, a2 = z, a3 = z;
        for (int v = 0; v < TOPK; ++v) {
            float w8 = twv[row][v];
            const f32x4* fr = (const f32x4*)(feats + (size_t)twi[row][v] * DF + c0);
            a0 += w8 * fr[0];
            a1 += w8 * fr[1];
            a2 += w8 * fr[2];
            a3 += w8 * fr[3];
        }
        f32x4* op = (f32x4*)(outg + (size_t)(s0 + row) * DF + c0);
        op[0] = a0;
        op[1] = a1;
        op[2] = a2;
        op[3] = a3;
    }
}

extern "C" void kernel_launch(void* const* d_in, const int* in_sizes, int n_in,
                              void* d_out, int out_size, void* d_ws, size_t ws_size,
                              hipStream_t stream) {
    const float* feats = (const float*)d_in[0];
    const int* ei = (const int*)d_in[1];
    float* out = (float*)d_out;

    int* outcnt = (int*)d_ws;                     // 2048
    int* indeg = outcnt + NN;                     // 2048
    int* cursor = indeg + NN;                     // 2048
    int* perm = cursor + NN;                      // 2048 (slot -> node id)
    int* invperm = perm + NN;                     // 2048 (node id -> slot)
    float* wvslot = (float*)(invperm + NN);       // 2048 (0.5/outdeg by slot)
    int* gmaxq = (int*)(wvslot + NN);             // 64 (32 used; keeps T 8B-aligned)
    unsigned* T = (unsigned*)(gmaxq + 64);        // 12*2048*2 words (quad-packed CSC, slot ids)

    init_kernel<<<(MAXDQ * NN * 2 + 255) / 256, 256, 0, stream>>>(outcnt, indeg, T);
    count_kernel<<<(NE + 255) / 256, 256, 0, stream>>>(ei, outcnt, indeg);
    meta_kernel<<<1, 256, 0, stream>>>(outcnt, indeg, perm, invperm, wvslot, gmaxq, cursor);
    fill_kernel<<<(NE + 255) / 256, 256, 0, stream>>>(ei, invperm, cursor, (unsigned short*)T);
    push_topk_kernel<<<NN / NSRC, 512, 0, stream>>>(T, wvslot, gmaxq, perm, invperm, feats, out);
}